// Round 19
// baseline (189.692 us; speedup 1.0000x reference)
//
#include <hip/hip_runtime.h>
#include <hip/hip_bf16.h>
#include <stdint.h>
#include <stddef.h>

#define B_N 4
#define S_N 2048
#define D_N 1024
#define H_N 16
#define HD_N 64

typedef __bf16 bf16;
typedef __bf16 bf16x8 __attribute__((ext_vector_type(8)));
typedef __bf16 bf16x4 __attribute__((ext_vector_type(4)));
typedef float f32x4 __attribute__((ext_vector_type(4)));

__device__ __forceinline__ void gload_lds16(const void* g, void* l) {
  __builtin_amdgcn_global_load_lds((const __attribute__((address_space(1))) void*)g,
                                   (__attribute__((address_space(3))) void*)l,
                                   16, 0, 0);
}

// ===== single conversion dispatch: x (blocks 0..2047) + 4 weights (2048..4095)
__global__ __launch_bounds__(256) void cvt_all(const float* __restrict__ x,
                                               const float* __restrict__ w0,
                                               const float* __restrict__ w1,
                                               const float* __restrict__ w2,
                                               const float* __restrict__ w3,
                                               bf16* __restrict__ xb,
                                               bf16* __restrict__ o0, bf16* __restrict__ o1,
                                               bf16* __restrict__ o2, bf16* __restrict__ o3) {
  const int bid = blockIdx.x;
  const float* in;
  bf16* out;
  int n4, i, stride;
  if (bid < 2048) {
    in = x; out = xb;
    n4 = (B_N * S_N * D_N) / 4;
    i = bid * 256 + threadIdx.x;
    stride = 2048 * 256;
  } else {
    const int which = (bid - 2048) >> 9;
    in = which == 0 ? w0 : which == 1 ? w1 : which == 2 ? w2 : w3;
    out = which == 0 ? o0 : which == 1 ? o1 : which == 2 ? o2 : o3;
    n4 = (D_N * D_N) / 4;
    i = ((bid - 2048) & 511) * 256 + threadIdx.x;
    stride = 512 * 256;
  }
  for (; i < n4; i += stride) {
    const float4 v = ((const float4*)in)[i];
    bf16x4 o;
    o[0] = (bf16)v.x; o[1] = (bf16)v.y; o[2] = (bf16)v.z; o[3] = (bf16)v.w;
    ((bf16x4*)out)[i] = o;
  }
}

// ===== Fused Q+K+V projection, shared-A staging, 2 blocks/CU ===============
// 256 threads (4 waves, 2Mx2N of 64x64 per w), BM=128 BN=128 BK=32.
// 2-buffer LDS (64KB). Counted vmcnt(8), never 0 in main loop.
// XCD-local A-panels: 1D grid 512, xcd=bid&7 gets m-panels [xcd*8,xcd*8+8).
__global__ __launch_bounds__(256, 2) void gemm_qkv3(const bf16* __restrict__ A,
                                                    const bf16* __restrict__ Wq,
                                                    const bf16* __restrict__ Wk,
                                                    const bf16* __restrict__ Wv,
                                                    const float* __restrict__ bq,
                                                    const float* __restrict__ bk,
                                                    const float* __restrict__ bv,
                                                    bf16* __restrict__ outQ,
                                                    bf16* __restrict__ outK,
                                                    bf16* __restrict__ outVt) {
  // per buffer: A 128x32 (8KB) @0, B 3x128x32 (24KB) @8192; stride 32768
  __shared__ __align__(16) char smem[2 * 32768];
  const int tid = threadIdx.x;
  const int wid = tid >> 6;   // 0..3
  const int lane = tid & 63;
  const int l16 = lane & 15;
  const int lhi = lane >> 4;
  const int bid = blockIdx.x;          // [0,512)
  const int xcd = bid & 7;
  const int s = bid >> 3;
  const int m0 = ((xcd << 3) | (s & 7)) * 128;  // A row-panel, XCD-local
  const int n0 = (s >> 3) * 128;                // W col-panel

  const int wm = (wid >> 1) * 64;
  const int wn = (wid & 1) * 64;
  const int srow4 = lane >> 2;                      // 0..15
  const int scol = 8 * ((lane & 3) ^ (srow4 & 3));  // pre-swizzled source elems
  const int rswz = (lhi ^ (l16 & 3)) * 16;          // read swizzle, bytes

  f32x4 acc[3][4][4];
#pragma unroll
  for (int w = 0; w < 3; ++w)
#pragma unroll
    for (int i = 0; i < 4; ++i)
#pragma unroll
      for (int j = 0; j < 4; ++j) acc[w][i][j] = (f32x4){0.f, 0.f, 0.f, 0.f};

#define STG(buf_, kt_)                                                                    \
  {                                                                                       \
    _Pragma("unroll") for (int q = 0; q < 2; ++q)                                         \
        gload_lds16(A + (size_t)(m0 + q * 64 + wid * 16 + srow4) * D_N + (kt_)*32 + scol, \
                    smem + (buf_)*32768 + q * 4096 + wid * 1024);                         \
    _Pragma("unroll") for (int q = 0; q < 2; ++q) {                                       \
      gload_lds16(Wq + (size_t)(n0 + q * 64 + wid * 16 + srow4) * D_N + (kt_)*32 + scol,  \
                  smem + (buf_)*32768 + 8192 + q * 4096 + wid * 1024);                    \
      gload_lds16(Wk + (size_t)(n0 + q * 64 + wid * 16 + srow4) * D_N + (kt_)*32 + scol,  \
                  smem + (buf_)*32768 + 16384 + q * 4096 + wid * 1024);                   \
      gload_lds16(Wv + (size_t)(n0 + q * 64 + wid * 16 + srow4) * D_N + (kt_)*32 + scol,  \
                  smem + (buf_)*32768 + 24576 + q * 4096 + wid * 1024);                   \
    }                                                                                     \
  }

#define PHASE(buf_)                                                                       \
  {                                                                                       \
    const char* a_ = smem + (buf_)*32768;                                                 \
    const char* b_ = a_ + 8192;                                                           \
    bf16x8 af[4];                                                                         \
    _Pragma("unroll") for (int i = 0; i < 4; ++i)                                         \
        af[i] = *(const bf16x8*)(a_ + (wm + i * 16 + l16) * 64 + rswz);                   \
    _Pragma("unroll") for (int w = 0; w < 3; ++w) {                                       \
      bf16x8 bfr[4];                                                                      \
      _Pragma("unroll") for (int j = 0; j < 4; ++j)                                       \
          bfr[j] = *(const bf16x8*)(b_ + (w * 128 + wn + j * 16 + l16) * 64 + rswz);      \
      __builtin_amdgcn_s_setprio(1);                                                      \
      _Pragma("unroll") for (int i = 0; i < 4; ++i)                                       \
          _Pragma("unroll") for (int j = 0; j < 4; ++j)                                   \
              acc[w][i][j] = __builtin_amdgcn_mfma_f32_16x16x32_bf16(af[i], bfr[j],       \
                                                                     acc[w][i][j], 0, 0, 0); \
      __builtin_amdgcn_s_setprio(0);                                                      \
    }                                                                                     \
  }

  const int NT = D_N / 32;  // 32; tile t lives in buffer t&1

  STG(0, 0);
  STG(1, 1);
  asm volatile("s_waitcnt vmcnt(8)" ::: "memory");  // tile 0 landed (tile 1 in flight)
  asm volatile("s_barrier" ::: "memory");

  for (int t = 0; t < NT - 2; ++t) {
    const int cur = t & 1;
    PHASE(cur);
    asm volatile("s_barrier" ::: "memory");          // all waves done reading buf cur
    STG(cur, t + 2);                                 // overwrite cur with tile t+2
    asm volatile("s_waitcnt vmcnt(8)" ::: "memory"); // tile t+1's 8 landed
    asm volatile("s_barrier" ::: "memory");          // publish t+1
  }
  PHASE(0);                                          // t = 30
  asm volatile("s_waitcnt vmcnt(0)" ::: "memory");   // tile 31 landed
  asm volatile("s_barrier" ::: "memory");
  PHASE(1);                                          // t = 31

#undef STG
#undef PHASE

#pragma unroll
  for (int w = 0; w < 3; ++w) {
    const float* bias = w == 0 ? bq : w == 1 ? bk : bv;
#pragma unroll
    for (int i = 0; i < 4; ++i) {
#pragma unroll
      for (int j = 0; j < 4; ++j) {
        const int row0 = m0 + wm + i * 16 + lhi * 4;
        const int col = n0 + wn + j * 16 + l16;
        const float bvv = bias[col];
        const int h = col >> 6, hd = col & 63;
        if (w == 2) {
          const int b = row0 >> 11, s2 = row0 & (S_N - 1);
          bf16x4 pk;
#pragma unroll
          for (int r = 0; r < 4; ++r) pk[r] = (bf16)(acc[w][i][j][r] + bvv);
          *(bf16x4*)&outVt[(((size_t)b * H_N + h) * HD_N + hd) * S_N + s2] = pk;
        } else {
          bf16* out = w == 0 ? outQ : outK;
#pragma unroll
          for (int r = 0; r < 4; ++r) {
            const int row = row0 + r;
            const int b = row >> 11, s2 = row & (S_N - 1);
            out[(((size_t)b * H_N + h) * S_N + s2) * HD_N + hd] = (bf16)(acc[w][i][j][r] + bvv);
          }
        }
      }
    }
  }
}

// ===== O-projection (2-buffer, 3 blocks/CU), XCD-local A-panels =============
__global__ __launch_bounds__(256, 3) void gemm_out(const bf16* __restrict__ A,
                                                   const bf16* __restrict__ W,
                                                   const float* __restrict__ bias,
                                                   float* __restrict__ out) {
  // per buffer: A 128x32 (8KB) @0, B 128x32 (8KB) @8192; stride 16384
  __shared__ __align__(16) char smem[2 * 16384];
  const int tid = threadIdx.x;
  const int wid = tid >> 6;
  const int lane = tid & 63;
  const int l16 = lane & 15;
  const int lhi = lane >> 4;
  const int bid = blockIdx.x;          // [0,512)
  const int xcd = bid & 7;
  const int s = bid >> 3;
  const int m0 = ((xcd << 3) | (s & 7)) * 128;  // A 2MB + W 2MB = 4MB/XCD (L2-fit)
  const int n0 = (s >> 3) * 128;

  const int wm = (wid >> 1) * 64;
  const int wn = (wid & 1) * 64;
  const int srow4 = lane >> 2;
  const int scol = 8 * ((lane & 3) ^ (srow4 & 3));
  const int rswz = (lhi ^ (l16 & 3)) * 16;

  f32x4 acc[4][4];
#pragma unroll
  for (int i = 0; i < 4; ++i)
#pragma unroll
    for (int j = 0; j < 4; ++j) acc[i][j] = (f32x4){0.f, 0.f, 0.f, 0.f};

#define STG(buf_, kt_)                                                                    \
  {                                                                                       \
    _Pragma("unroll") for (int q = 0; q < 2; ++q) {                                       \
      gload_lds16(A + (size_t)(m0 + q * 64 + wid * 16 + srow4) * D_N + (kt_)*32 + scol,   \
                  smem + (buf_)*16384 + q * 4096 + wid * 1024);                           \
      gload_lds16(W + (size_t)(n0 + q * 64 + wid * 16 + srow4) * D_N + (kt_)*32 + scol,   \
                  smem + (buf_)*16384 + 8192 + q * 4096 + wid * 1024);                    \
    }                                                                                     \
  }

#define PHASE(buf_)                                                                       \
  {                                                                                       \
    const char* a_ = smem + (buf_)*16384;                                                 \
    const char* b_ = a_ + 8192;                                                           \
    bf16x8 af[4], bfr[4];                                                                 \
    _Pragma("unroll") for (int i = 0; i < 4; ++i)                                         \
        af[i] = *(const bf16x8*)(a_ + (wm + i * 16 + l16) * 64 + rswz);                   \
    _Pragma("unroll") for (int j = 0; j < 4; ++j)                                         \
        bfr[j] = *(const bf16x8*)(b_ + (wn + j * 16 + l16) * 64 + rswz);                  \
    __builtin_amdgcn_s_setprio(1);                                                        \
    _Pragma("unroll") for (int i = 0; i < 4; ++i)                                         \
        _Pragma("unroll") for (int j = 0; j < 4; ++j)                                     \
            acc[i][j] = __builtin_amdgcn_mfma_f32_16x16x32_bf16(af[i], bfr[j],            \
                                                                acc[i][j], 0, 0, 0);      \
    __builtin_amdgcn_s_setprio(0);                                                        \
  }

  const int NT = D_N / 32;

  STG(0, 0);
  STG(1, 1);
  asm volatile("s_waitcnt vmcnt(4)" ::: "memory");
  asm volatile("s_barrier" ::: "memory");

  for (int t = 0; t < NT - 2; ++t) {
    const int cur = t & 1;
    PHASE(cur);
    asm volatile("s_barrier" ::: "memory");
    STG(cur, t + 2);
    asm volatile("s_waitcnt vmcnt(4)" ::: "memory");
    asm volatile("s_barrier" ::: "memory");
  }
  PHASE(0);
  asm volatile("s_waitcnt vmcnt(0)" ::: "memory");
  asm volatile("s_barrier" ::: "memory");
  PHASE(1);

#undef STG
#undef PHASE

#pragma unroll
  for (int i = 0; i < 4; ++i) {
#pragma unroll
    for (int j = 0; j < 4; ++j) {
      const int row0 = m0 + wm + i * 16 + lhi * 4;
      const int col = n0 + wn + j * 16 + l16;
      const float bvv = bias[col];
#pragma unroll
      for (int r = 0; r < 4; ++r) out[(size_t)(row0 + r) * D_N + col] = acc[i][j][r] + bvv;
    }
  }
}

// Causal attention, round-19: QBLK=64 rows/wave (4 i-tiles) -> 72 MFMA per
// K/V-tile per wave (2x chain density), staging/barriers per FLOP halved.
// 512 blocks, qt-pairing (pq and 7-pq) -> all blocks equal work, exactly
// 2 blocks/CU. XCD-local heads (bh=bid&63). Fixed-max softmax, raw v_exp.
__global__ __launch_bounds__(256, 2) void attn_fwd(const bf16* __restrict__ Q,
                                                   const bf16* __restrict__ K,
                                                   const bf16* __restrict__ Vt,
                                                   bf16* __restrict__ O) {
  __shared__ __align__(16) bf16 sK[2][64 * 64];
  __shared__ __align__(16) bf16 sV[2][64 * 64];
  __shared__ __align__(16) bf16 sP[4][64 * 72];
  const int tid = threadIdx.x;
  const int wave = tid >> 6;
  const int lane = tid & 63;
  const int l16 = lane & 15;
  const int lhi = lane >> 4;
  const int bidx = blockIdx.x;       // [0,512)
  const int bh = bidx & 63;          // XCD = bidx%8 = bh%8 -> 8 heads/XCD (L2-fit)
  const int pq = bidx >> 6;          // [0,8): q-supertiles pq and 7-pq
  const bf16* Qh = Q + (size_t)bh * S_N * HD_N;
  const bf16* Kh = K + (size_t)bh * S_N * HD_N;
  const bf16* Vth = Vt + (size_t)bh * HD_N * S_N;
  const int b = bh >> 4, h = bh & 15;

  const int srow = lane >> 3;
  const int scol = 8 * ((lane & 7) ^ srow);

  const float QS = 0.03125f * 1.44269504088896340736f;
  const f32x4 z4 = {0.0f, 0.0f, 0.0f, 0.0f};
  const f32x4 m4 = {-4.0f, -4.0f, -4.0f, -4.0f};
  const bf16 oneb = (bf16)1.0f;
  const bf16x8 ones = {oneb, oneb, oneb, oneb, oneb, oneb, oneb, oneb};
  bf16* sPw = sP[wave];

#define STAGE(buf, kb_)                                                                  \
  {                                                                                      \
    _Pragma("unroll") for (int is = 0; is < 2; ++is) {                                   \
      const int r0 = is * 32 + wave * 8;                                                 \
      gload_lds16(Kh + (size_t)((kb_)*64 + r0 + srow) * HD_N + scol, &sK[buf][r0 * 64]); \
      gload_lds16(Vth + (size_t)(r0 + srow) * S_N + (kb_)*64 + scol, &sV[buf][r0 * 64]); \
    }                                                                                    \
  }

  for (int pass = 0; pass < 2; ++pass) {
    const int qt = pass ? (7 - pq) : pq;
    const int q0 = qt * 256 + wave * 64;

    // Q fragments (64 rows/wave), pre-scaled by log2(e)/sqrt(D)
    bf16x8 qf[4][2];
#pragma unroll
    for (int i = 0; i < 4; ++i)
#pragma unroll
      for (int kq = 0; kq < 2; ++kq) {
        const bf16x8 raw =
            *(const bf16x8*)&Qh[(size_t)(q0 + i * 16 + l16) * HD_N + kq * 32 + lhi * 8];
        bf16x8 sv;
#pragma unroll
        for (int e = 0; e < 8; ++e) sv[e] = (bf16)((float)raw[e] * QS);
        qf[i][kq] = sv;
      }

    f32x4 o[4][4];
    f32x4 osum[4];
#pragma unroll
    for (int i = 0; i < 4; ++i) {
#pragma unroll
      for (int j = 0; j < 4; ++j) o[i][j] = z4;
      osum[i] = z4;
    }

    const int nkb = 4 * qt + 4;  // block-level causal tile count (256 q-rows)

    STAGE(0, 0);
    __syncthreads();

    for (int kb = 0; kb < nkb; ++kb) {
      const int cur = kb & 1;
      if (kb + 1 < nkb) STAGE(cur ^ 1, kb + 1);
      const bf16* sKb = sK[cur];
      const bf16* sVb = sV[cur];
      const int k0 = kb * 64;

      if (k0 <= q0 + 63) {  // tile not fully masked for this wave
        f32x4 sc[4][4];
#pragma unroll
        for (int i = 0; i < 4; ++i)
#pragma unroll
          for (int j = 0; j < 4; ++j) sc[i][j] = m4;
        __builtin_amdgcn_s_setprio(1);
#pragma unroll
        for (int j = 0; j < 4; ++j) {
          const int row = j * 16 + l16;
#pragma unroll
          for (int kq = 0; kq < 2; ++kq) {
            const bf16x8 kfr = *(const bf16x8*)((const char*)sKb + row * 128 +
                                                ((kq * 64 + lhi * 16) ^ ((row & 7) << 4)));
#pragma unroll
            for (int i = 0; i < 4; ++i)
              sc[i][j] =
                  __builtin_amdgcn_mfma_f32_16x16x32_bf16(qf[i][kq], kfr, sc[i][j], 0, 0, 0);
          }
        }
        __builtin_amdgcn_s_setprio(0);

        if (k0 + 63 > q0) {
#pragma unroll
          for (int i = 0; i < 4; ++i)
#pragma unroll
            for (int r = 0; r < 4; ++r) {
              const int qrow = q0 + i * 16 + lhi * 4 + r;
#pragma unroll
              for (int j = 0; j < 4; ++j)
                if (k0 + j * 16 + l16 > qrow) sc[i][j][r] = -3e38f;
            }
        }

#pragma unroll
        for (int i = 0; i < 4; ++i)
#pragma unroll
          for (int r = 0; r < 4; ++r)
#pragma unroll
            for (int j = 0; j < 4; ++j)
              sPw[(i * 16 + lhi * 4 + r) * 72 + j * 16 + l16] =
                  (bf16)__builtin_amdgcn_exp2f(sc[i][j][r]);

        __builtin_amdgcn_s_setprio(1);
#pragma unroll
        for (int kq = 0; kq < 2; ++kq) {
          bf16x8 pa[4];
#pragma unroll
          for (int i = 0; i < 4; ++i)
            pa[i] = *(const bf16x8*)&sPw[(i * 16 + l16) * 72 + kq * 32 + lhi * 8];
#pragma unroll
          for (int i = 0; i < 4; ++i)
            osum[i] = __builtin_amdgcn_mfma_f32_16x16x32_bf16(pa[i], ones, osum[i], 0, 0, 0);
#pragma unroll
          for (int jd = 0; jd < 4; ++jd) {
            const int vrow = jd * 16 + l16;
            const bf16x8 vb = *(const bf16x8*)((const char*)sVb + vrow * 128 +
                                               ((kq * 64 + lhi * 16) ^ ((vrow & 7) << 4)));
#pragma unroll
            for (int i = 0; i < 4; ++i)
              o[i][jd] = __builtin_amdgcn_mfma_f32_16x16x32_bf16(pa[i], vb, o[i][jd], 0, 0, 0);
          }
        }
        __builtin_amdgcn_s_setprio(0);
      }
      __syncthreads();
    }

#pragma unroll
    for (int i = 0; i < 4; ++i) {
#pragma unroll
      for (int r = 0; r < 4; ++r) {
        const float inv = __builtin_amdgcn_rcpf(osum[i][r]);
        const size_t token = (size_t)b * S_N + q0 + i * 16 + lhi * 4 + r;
#pragma unroll
        for (int jd = 0; jd < 4; ++jd) {
          const int col = h * 64 + jd * 16 + l16;
          O[token * D_N + col] = (bf16)(o[i][jd][r] * inv);
        }
      }
    }
  }
#undef STAGE
}

extern "C" void kernel_launch(void* const* d_in, const int* in_sizes, int n_in,
                              void* d_out, int out_size, void* d_ws, size_t ws_size,
                              hipStream_t stream) {
  const float* x  = (const float*)d_in[0];
  const float* Wq = (const float*)d_in[1];
  const float* bq = (const float*)d_in[2];
  const float* Wk = (const float*)d_in[3];
  const float* bk = (const float*)d_in[4];
  const float* Wv = (const float*)d_in[5];
  const float* bv = (const float*)d_in[6];
  const float* Wo = (const float*)d_in[7];
  const float* bo = (const float*)d_in[8];

  char* ws = (char*)d_ws;
  const size_t MB = 1u << 20;
  bf16* xb  = (bf16*)(ws);               // 16 MB; reused as attn output
  bf16* qB  = (bf16*)(ws + 16 * MB);
  bf16* kB  = (bf16*)(ws + 32 * MB);
  bf16* vtB = (bf16*)(ws + 48 * MB);
  bf16* wqb = (bf16*)(ws + 64 * MB);
  bf16* wkb = (bf16*)(ws + 66 * MB);
  bf16* wvb = (bf16*)(ws + 68 * MB);
  bf16* wob = (bf16*)(ws + 70 * MB);

  cvt_all<<<4096, 256, 0, stream>>>(x, Wq, Wk, Wv, Wo, xb, wqb, wkb, wvb, wob);

  gemm_qkv3<<<dim3(512), 256, 0, stream>>>(xb, wqb, wkb, wvb, bq, bk, bv, qB, kB, vtB);

  attn_fwd<<<dim3(512), 256, 0, stream>>>(qB, kB, vtB, xb);

  gemm_out<<<dim3(512), 256, 0, stream>>>(xb, wob, bo, (float*)d_out);
}

// Round 20
// 148.089 us; speedup vs baseline: 1.2809x; 1.2809x over previous
//
#include <hip/hip_runtime.h>
#include <hip/hip_bf16.h>
#include <stdint.h>
#include <stddef.h>

#define B_N 4
#define S_N 2048
#define D_N 1024
#define H_N 16
#define HD_N 64

typedef __bf16 bf16;
typedef __bf16 bf16x8 __attribute__((ext_vector_type(8)));
typedef __bf16 bf16x4 __attribute__((ext_vector_type(4)));
typedef float f32x4 __attribute__((ext_vector_type(4)));

__device__ __forceinline__ void gload_lds16(const void* g, void* l) {
  __builtin_amdgcn_global_load_lds((const __attribute__((address_space(1))) void*)g,
                                   (__attribute__((address_space(3))) void*)l,
                                   16, 0, 0);
}

// ===== single conversion dispatch: x (blocks 0..2047) + 4 weights (2048..4095)
__global__ __launch_bounds__(256) void cvt_all(const float* __restrict__ x,
                                               const float* __restrict__ w0,
                                               const float* __restrict__ w1,
                                               const float* __restrict__ w2,
                                               const float* __restrict__ w3,
                                               bf16* __restrict__ xb,
                                               bf16* __restrict__ o0, bf16* __restrict__ o1,
                                               bf16* __restrict__ o2, bf16* __restrict__ o3) {
  const int bid = blockIdx.x;
  const float* in;
  bf16* out;
  int n4, i, stride;
  if (bid < 2048) {
    in = x; out = xb;
    n4 = (B_N * S_N * D_N) / 4;
    i = bid * 256 + threadIdx.x;
    stride = 2048 * 256;
  } else {
    const int which = (bid - 2048) >> 9;
    in = which == 0 ? w0 : which == 1 ? w1 : which == 2 ? w2 : w3;
    out = which == 0 ? o0 : which == 1 ? o1 : which == 2 ? o2 : o3;
    n4 = (D_N * D_N) / 4;
    i = ((bid - 2048) & 511) * 256 + threadIdx.x;
    stride = 512 * 256;
  }
  for (; i < n4; i += stride) {
    const float4 v = ((const float4*)in)[i];
    bf16x4 o;
    o[0] = (bf16)v.x; o[1] = (bf16)v.y; o[2] = (bf16)v.z; o[3] = (bf16)v.w;
    ((bf16x4*)out)[i] = o;
  }
}

// ===== Fused Q+K+V projection, shared-A staging, 2 blocks/CU ===============
// 256 threads (4 waves, 2Mx2N of 64x64 per w), BM=128 BN=128 BK=32.
// 2-buffer LDS (64KB). Counted vmcnt(8), never 0 in main loop.
// XCD-local A-panels: 1D grid 512, xcd=bid&7 gets m-panels [xcd*8,xcd*8+8).
__global__ __launch_bounds__(256, 2) void gemm_qkv3(const bf16* __restrict__ A,
                                                    const bf16* __restrict__ Wq,
                                                    const bf16* __restrict__ Wk,
                                                    const bf16* __restrict__ Wv,
                                                    const float* __restrict__ bq,
                                                    const float* __restrict__ bk,
                                                    const float* __restrict__ bv,
                                                    bf16* __restrict__ outQ,
                                                    bf16* __restrict__ outK,
                                                    bf16* __restrict__ outVt) {
  // per buffer: A 128x32 (8KB) @0, B 3x128x32 (24KB) @8192; stride 32768
  __shared__ __align__(16) char smem[2 * 32768];
  const int tid = threadIdx.x;
  const int wid = tid >> 6;   // 0..3
  const int lane = tid & 63;
  const int l16 = lane & 15;
  const int lhi = lane >> 4;
  const int bid = blockIdx.x;          // [0,512)
  const int xcd = bid & 7;
  const int s = bid >> 3;
  const int m0 = ((xcd << 3) | (s & 7)) * 128;  // A row-panel, XCD-local
  const int n0 = (s >> 3) * 128;                // W col-panel

  const int wm = (wid >> 1) * 64;
  const int wn = (wid & 1) * 64;
  const int srow4 = lane >> 2;                      // 0..15
  const int scol = 8 * ((lane & 3) ^ (srow4 & 3));  // pre-swizzled source elems
  const int rswz = (lhi ^ (l16 & 3)) * 16;          // read swizzle, bytes

  f32x4 acc[3][4][4];
#pragma unroll
  for (int w = 0; w < 3; ++w)
#pragma unroll
    for (int i = 0; i < 4; ++i)
#pragma unroll
      for (int j = 0; j < 4; ++j) acc[w][i][j] = (f32x4){0.f, 0.f, 0.f, 0.f};

#define STG(buf_, kt_)                                                                    \
  {                                                                                       \
    _Pragma("unroll") for (int q = 0; q < 2; ++q)                                         \
        gload_lds16(A + (size_t)(m0 + q * 64 + wid * 16 + srow4) * D_N + (kt_)*32 + scol, \
                    smem + (buf_)*32768 + q * 4096 + wid * 1024);                         \
    _Pragma("unroll") for (int q = 0; q < 2; ++q) {                                       \
      gload_lds16(Wq + (size_t)(n0 + q * 64 + wid * 16 + srow4) * D_N + (kt_)*32 + scol,  \
                  smem + (buf_)*32768 + 8192 + q * 4096 + wid * 1024);                    \
      gload_lds16(Wk + (size_t)(n0 + q * 64 + wid * 16 + srow4) * D_N + (kt_)*32 + scol,  \
                  smem + (buf_)*32768 + 16384 + q * 4096 + wid * 1024);                   \
      gload_lds16(Wv + (size_t)(n0 + q * 64 + wid * 16 + srow4) * D_N + (kt_)*32 + scol,  \
                  smem + (buf_)*32768 + 24576 + q * 4096 + wid * 1024);                   \
    }                                                                                     \
  }

#define PHASE(buf_)                                                                       \
  {                                                                                       \
    const char* a_ = smem + (buf_)*32768;                                                 \
    const char* b_ = a_ + 8192;                                                           \
    bf16x8 af[4];                                                                         \
    _Pragma("unroll") for (int i = 0; i < 4; ++i)                                         \
        af[i] = *(const bf16x8*)(a_ + (wm + i * 16 + l16) * 64 + rswz);                   \
    _Pragma("unroll") for (int w = 0; w < 3; ++w) {                                       \
      bf16x8 bfr[4];                                                                      \
      _Pragma("unroll") for (int j = 0; j < 4; ++j)                                       \
          bfr[j] = *(const bf16x8*)(b_ + (w * 128 + wn + j * 16 + l16) * 64 + rswz);      \
      __builtin_amdgcn_s_setprio(1);                                                      \
      _Pragma("unroll") for (int i = 0; i < 4; ++i)                                       \
          _Pragma("unroll") for (int j = 0; j < 4; ++j)                                   \
              acc[w][i][j] = __builtin_amdgcn_mfma_f32_16x16x32_bf16(af[i], bfr[j],       \
                                                                     acc[w][i][j], 0, 0, 0); \
      __builtin_amdgcn_s_setprio(0);                                                      \
    }                                                                                     \
  }

  const int NT = D_N / 32;  // 32; tile t lives in buffer t&1

  STG(0, 0);
  STG(1, 1);
  asm volatile("s_waitcnt vmcnt(8)" ::: "memory");  // tile 0 landed (tile 1 in flight)
  asm volatile("s_barrier" ::: "memory");

  for (int t = 0; t < NT - 2; ++t) {
    const int cur = t & 1;
    PHASE(cur);
    asm volatile("s_barrier" ::: "memory");          // all waves done reading buf cur
    STG(cur, t + 2);                                 // overwrite cur with tile t+2
    asm volatile("s_waitcnt vmcnt(8)" ::: "memory"); // tile t+1's 8 landed
    asm volatile("s_barrier" ::: "memory");          // publish t+1
  }
  PHASE(0);                                          // t = 30
  asm volatile("s_waitcnt vmcnt(0)" ::: "memory");   // tile 31 landed
  asm volatile("s_barrier" ::: "memory");
  PHASE(1);                                          // t = 31

#undef STG
#undef PHASE

#pragma unroll
  for (int w = 0; w < 3; ++w) {
    const float* bias = w == 0 ? bq : w == 1 ? bk : bv;
#pragma unroll
    for (int i = 0; i < 4; ++i) {
#pragma unroll
      for (int j = 0; j < 4; ++j) {
        const int row0 = m0 + wm + i * 16 + lhi * 4;
        const int col = n0 + wn + j * 16 + l16;
        const float bvv = bias[col];
        const int h = col >> 6, hd = col & 63;
        if (w == 2) {
          const int b = row0 >> 11, s2 = row0 & (S_N - 1);
          bf16x4 pk;
#pragma unroll
          for (int r = 0; r < 4; ++r) pk[r] = (bf16)(acc[w][i][j][r] + bvv);
          *(bf16x4*)&outVt[(((size_t)b * H_N + h) * HD_N + hd) * S_N + s2] = pk;
        } else {
          bf16* out = w == 0 ? outQ : outK;
#pragma unroll
          for (int r = 0; r < 4; ++r) {
            const int row = row0 + r;
            const int b = row >> 11, s2 = row & (S_N - 1);
            out[(((size_t)b * H_N + h) * S_N + s2) * HD_N + hd] = (bf16)(acc[w][i][j][r] + bvv);
          }
        }
      }
    }
  }
}

// ===== O-projection (2-buffer, 3 blocks/CU), XCD-local A-panels =============
__global__ __launch_bounds__(256, 3) void gemm_out(const bf16* __restrict__ A,
                                                   const bf16* __restrict__ W,
                                                   const float* __restrict__ bias,
                                                   float* __restrict__ out) {
  // per buffer: A 128x32 (8KB) @0, B 128x32 (8KB) @8192; stride 16384
  __shared__ __align__(16) char smem[2 * 16384];
  const int tid = threadIdx.x;
  const int wid = tid >> 6;
  const int lane = tid & 63;
  const int l16 = lane & 15;
  const int lhi = lane >> 4;
  const int bid = blockIdx.x;          // [0,512)
  const int xcd = bid & 7;
  const int s = bid >> 3;
  const int m0 = ((xcd << 3) | (s & 7)) * 128;  // A 2MB + W 2MB = 4MB/XCD (L2-fit)
  const int n0 = (s >> 3) * 128;

  const int wm = (wid >> 1) * 64;
  const int wn = (wid & 1) * 64;
  const int srow4 = lane >> 2;
  const int scol = 8 * ((lane & 3) ^ (srow4 & 3));
  const int rswz = (lhi ^ (l16 & 3)) * 16;

  f32x4 acc[4][4];
#pragma unroll
  for (int i = 0; i < 4; ++i)
#pragma unroll
    for (int j = 0; j < 4; ++j) acc[i][j] = (f32x4){0.f, 0.f, 0.f, 0.f};

#define STG(buf_, kt_)                                                                    \
  {                                                                                       \
    _Pragma("unroll") for (int q = 0; q < 2; ++q) {                                       \
      gload_lds16(A + (size_t)(m0 + q * 64 + wid * 16 + srow4) * D_N + (kt_)*32 + scol,   \
                  smem + (buf_)*16384 + q * 4096 + wid * 1024);                           \
      gload_lds16(W + (size_t)(n0 + q * 64 + wid * 16 + srow4) * D_N + (kt_)*32 + scol,   \
                  smem + (buf_)*16384 + 8192 + q * 4096 + wid * 1024);                    \
    }                                                                                     \
  }

#define PHASE(buf_)                                                                       \
  {                                                                                       \
    const char* a_ = smem + (buf_)*16384;                                                 \
    const char* b_ = a_ + 8192;                                                           \
    bf16x8 af[4], bfr[4];                                                                 \
    _Pragma("unroll") for (int i = 0; i < 4; ++i)                                         \
        af[i] = *(const bf16x8*)(a_ + (wm + i * 16 + l16) * 64 + rswz);                   \
    _Pragma("unroll") for (int j = 0; j < 4; ++j)                                         \
        bfr[j] = *(const bf16x8*)(b_ + (wn + j * 16 + l16) * 64 + rswz);                  \
    __builtin_amdgcn_s_setprio(1);                                                        \
    _Pragma("unroll") for (int i = 0; i < 4; ++i)                                         \
        _Pragma("unroll") for (int j = 0; j < 4; ++j)                                     \
            acc[i][j] = __builtin_amdgcn_mfma_f32_16x16x32_bf16(af[i], bfr[j],            \
                                                                acc[i][j], 0, 0, 0);      \
    __builtin_amdgcn_s_setprio(0);                                                        \
  }

  const int NT = D_N / 32;

  STG(0, 0);
  STG(1, 1);
  asm volatile("s_waitcnt vmcnt(4)" ::: "memory");
  asm volatile("s_barrier" ::: "memory");

  for (int t = 0; t < NT - 2; ++t) {
    const int cur = t & 1;
    PHASE(cur);
    asm volatile("s_barrier" ::: "memory");
    STG(cur, t + 2);
    asm volatile("s_waitcnt vmcnt(4)" ::: "memory");
    asm volatile("s_barrier" ::: "memory");
  }
  PHASE(0);
  asm volatile("s_waitcnt vmcnt(0)" ::: "memory");
  asm volatile("s_barrier" ::: "memory");
  PHASE(1);

#undef STG
#undef PHASE

#pragma unroll
  for (int i = 0; i < 4; ++i) {
#pragma unroll
    for (int j = 0; j < 4; ++j) {
      const int row0 = m0 + wm + i * 16 + lhi * 4;
      const int col = n0 + wn + j * 16 + l16;
      const float bvv = bias[col];
#pragma unroll
      for (int r = 0; r < 4; ++r) out[(size_t)(row0 + r) * D_N + col] = acc[i][j][r] + bvv;
    }
  }
}

// Causal attention (round-18 structure, reverted): block-shared swizzled
// K/V LDS staging, fixed-max softmax, raw v_exp_f32, XCD-local heads.
__global__ __launch_bounds__(256, 3) void attn_fwd(const bf16* __restrict__ Q,
                                                   const bf16* __restrict__ K,
                                                   const bf16* __restrict__ Vt,
                                                   bf16* __restrict__ O) {
  __shared__ __align__(16) bf16 sK[2][64 * 64];
  __shared__ __align__(16) bf16 sV[2][64 * 64];
  __shared__ __align__(16) bf16 sP[4][32 * 72];
  const int tid = threadIdx.x;
  const int wave = tid >> 6;
  const int lane = tid & 63;
  const int l16 = lane & 15;
  const int lhi = lane >> 4;
  const int bidx = blockIdx.x;       // [0,1024)
  const int bh = bidx & 63;          // XCD = bidx%8 = bh%8 -> 8 heads/XCD (L2-fit)
  const int qt = 15 - (bidx >> 6);   // heavy q-tiles first
  const int q0 = qt * 128 + wave * 32;
  const bf16* Qh = Q + (size_t)bh * S_N * HD_N;
  const bf16* Kh = K + (size_t)bh * S_N * HD_N;
  const bf16* Vth = Vt + (size_t)bh * HD_N * S_N;
  const int b = bh >> 4, h = bh & 15;

  const int srow = lane >> 3;
  const int scol = 8 * ((lane & 7) ^ srow);

  const float QS = 0.03125f * 1.44269504088896340736f;
  const f32x4 z4 = {0.0f, 0.0f, 0.0f, 0.0f};
  const f32x4 m4 = {-4.0f, -4.0f, -4.0f, -4.0f};
  const bf16 oneb = (bf16)1.0f;
  const bf16x8 ones = {oneb, oneb, oneb, oneb, oneb, oneb, oneb, oneb};
  bf16* sPw = sP[wave];

  bf16x8 qf[2][2];
#pragma unroll
  for (int i = 0; i < 2; ++i)
#pragma unroll
    for (int kq = 0; kq < 2; ++kq) {
      const bf16x8 raw =
          *(const bf16x8*)&Qh[(size_t)(q0 + i * 16 + l16) * HD_N + kq * 32 + lhi * 8];
      bf16x8 s;
#pragma unroll
      for (int e = 0; e < 8; ++e) s[e] = (bf16)((float)raw[e] * QS);
      qf[i][kq] = s;
    }

  f32x4 o[2][4];
  f32x4 osum[2];
#pragma unroll
  for (int i = 0; i < 2; ++i) {
#pragma unroll
    for (int j = 0; j < 4; ++j) o[i][j] = z4;
    osum[i] = z4;
  }

#define STAGE(buf, kb_)                                                                  \
  {                                                                                      \
    _Pragma("unroll") for (int is = 0; is < 2; ++is) {                                   \
      const int r0 = is * 32 + wave * 8;                                                 \
      gload_lds16(Kh + (size_t)((kb_)*64 + r0 + srow) * HD_N + scol, &sK[buf][r0 * 64]); \
      gload_lds16(Vth + (size_t)(r0 + srow) * S_N + (kb_)*64 + scol, &sV[buf][r0 * 64]); \
    }                                                                                    \
  }

  const int nkb = 2 * qt + 2;

  STAGE(0, 0);
  __syncthreads();

  for (int kb = 0; kb < nkb; ++kb) {
    const int cur = kb & 1;
    if (kb + 1 < nkb) STAGE(cur ^ 1, kb + 1);
    const bf16* sKb = sK[cur];
    const bf16* sVb = sV[cur];
    const int k0 = kb * 64;

    if (k0 <= q0 + 31) {
      f32x4 sc[2][4];
#pragma unroll
      for (int i = 0; i < 2; ++i)
#pragma unroll
        for (int j = 0; j < 4; ++j) sc[i][j] = m4;
      __builtin_amdgcn_s_setprio(1);
#pragma unroll
      for (int j = 0; j < 4; ++j) {
        const int row = j * 16 + l16;
#pragma unroll
        for (int kq = 0; kq < 2; ++kq) {
          const bf16x8 kfr = *(const bf16x8*)((const char*)sKb + row * 128 +
                                              ((kq * 64 + lhi * 16) ^ ((row & 7) << 4)));
#pragma unroll
          for (int i = 0; i < 2; ++i)
            sc[i][j] = __builtin_amdgcn_mfma_f32_16x16x32_bf16(qf[i][kq], kfr, sc[i][j], 0, 0, 0);
        }
      }
      __builtin_amdgcn_s_setprio(0);

      if (k0 + 63 > q0) {
#pragma unroll
        for (int i = 0; i < 2; ++i)
#pragma unroll
          for (int r = 0; r < 4; ++r) {
            const int qrow = q0 + i * 16 + lhi * 4 + r;
#pragma unroll
            for (int j = 0; j < 4; ++j)
              if (k0 + j * 16 + l16 > qrow) sc[i][j][r] = -3e38f;
          }
      }

#pragma unroll
      for (int i = 0; i < 2; ++i)
#pragma unroll
        for (int r = 0; r < 4; ++r)
#pragma unroll
          for (int j = 0; j < 4; ++j)
            sPw[(i * 16 + lhi * 4 + r) * 72 + j * 16 + l16] =
                (bf16)__builtin_amdgcn_exp2f(sc[i][j][r]);

      __builtin_amdgcn_s_setprio(1);
#pragma unroll
      for (int kq = 0; kq < 2; ++kq) {
        bf16x8 pa[2];
#pragma unroll
        for (int i = 0; i < 2; ++i)
          pa[i] = *(const bf16x8*)&sPw[(i * 16 + l16) * 72 + kq * 32 + lhi * 8];
#pragma unroll
        for (int i = 0; i < 2; ++i)
          osum[i] = __builtin_amdgcn_mfma_f32_16x16x32_bf16(pa[i], ones, osum[i], 0, 0, 0);
#pragma unroll
        for (int jd = 0; jd < 4; ++jd) {
          const int vrow = jd * 16 + l16;
          const bf16x8 vb = *(const bf16x8*)((const char*)sVb + vrow * 128 +
                                             ((kq * 64 + lhi * 16) ^ ((vrow & 7) << 4)));
#pragma unroll
          for (int i = 0; i < 2; ++i)
            o[i][jd] = __builtin_amdgcn_mfma_f32_16x16x32_bf16(pa[i], vb, o[i][jd], 0, 0, 0);
        }
      }
      __builtin_amdgcn_s_setprio(0);
    }
    __syncthreads();
  }

#pragma unroll
  for (int i = 0; i < 2; ++i) {
#pragma unroll
    for (int r = 0; r < 4; ++r) {
      const float inv = __builtin_amdgcn_rcpf(osum[i][r]);
      const size_t token = (size_t)b * S_N + q0 + i * 16 + lhi * 4 + r;
#pragma unroll
      for (int jd = 0; jd < 4; ++jd) {
        const int col = h * 64 + jd * 16 + l16;
        O[token * D_N + col] = (bf16)(o[i][jd][r] * inv);
      }
    }
  }
#undef STAGE
}

extern "C" void kernel_launch(void* const* d_in, const int* in_sizes, int n_in,
                              void* d_out, int out_size, void* d_ws, size_t ws_size,
                              hipStream_t stream) {
  const float* x  = (const float*)d_in[0];
  const float* Wq = (const float*)d_in[1];
  const float* bq = (const float*)d_in[2];
  const float* Wk = (const float*)d_in[3];
  const float* bk = (const float*)d_in[4];
  const float* Wv = (const float*)d_in[5];
  const float* bv = (const float*)d_in[6];
  const float* Wo = (const float*)d_in[7];
  const float* bo = (const float*)d_in[8];

  char* ws = (char*)d_ws;
  const size_t MB = 1u << 20;
  bf16* xb  = (bf16*)(ws);               // 16 MB; reused as attn output
  bf16* qB  = (bf16*)(ws + 16 * MB);
  bf16* kB  = (bf16*)(ws + 32 * MB);
  bf16* vtB = (bf16*)(ws + 48 * MB);
  bf16* wqb = (bf16*)(ws + 64 * MB);
  bf16* wkb = (bf16*)(ws + 66 * MB);
  bf16* wvb = (bf16*)(ws + 68 * MB);
  bf16* wob = (bf16*)(ws + 70 * MB);

  cvt_all<<<4096, 256, 0, stream>>>(x, Wq, Wk, Wv, Wo, xb, wqb, wkb, wvb, wob);

  gemm_qkv3<<<dim3(512), 256, 0, stream>>>(xb, wqb, wkb, wvb, bq, bk, bv, qB, kB, vtB);

  attn_fwd<<<dim3(1024), 256, 0, stream>>>(qB, kB, vtB, xb);

  gemm_out<<<dim3(512), 256, 0, stream>>>(xb, wob, bo, (float*)d_out);
}